// Round 3
// baseline (283.955 us; speedup 1.0000x reference)
//
#include <hip/hip_runtime.h>
#include <hip/hip_bf16.h>
#include <stdint.h>

#define M_DIM 8192
#define N_DIM 4096
#define K_DIM 4096

#define NT 64              // K-tiles of BK=64

using f32x16 = __attribute__((ext_vector_type(16))) float;
using bf16x8 = __attribute__((ext_vector_type(8))) __bf16;

typedef const __attribute__((address_space(1))) void glb_void_t;
typedef __attribute__((address_space(3))) void lds_void_t;

__device__ __forceinline__ void async16(const void* g, void* l) {
    // direct global->LDS, 16B per lane (dest = wave-uniform base + lane*16)
    __builtin_amdgcn_global_load_lds((glb_void_t*)(uintptr_t)g,
                                     (lds_void_t*)(uint32_t)(uintptr_t)l,
                                     16, 0, 0);
}

__device__ __forceinline__ unsigned short f32_to_bf16_rne(float f) {
    union { float f; uint32_t u; } v; v.f = f;
    uint32_t u = v.u;
    u += 0x7FFFu + ((u >> 16) & 1u);
    return (unsigned short)(u >> 16);
}

__device__ __forceinline__ unsigned short sign_to_bf16(float f) {
    union { float f; uint32_t u; } v; v.f = f;
    if ((v.u & 0x7FFFFFFFu) == 0u) return 0;                      // sign(0) = 0
    return (unsigned short)(0x3F80u | ((v.u >> 16) & 0x8000u));   // +-1.0 bf16
}

// ---- Phase 1: conversions (memory-bound, 16B loads / 16B stores) ----

__global__ void convert_x_kernel(const float* __restrict__ x,
                                 unsigned short* __restrict__ xb, int n8) {
    int stride = gridDim.x * blockDim.x;
    for (int i = blockIdx.x * blockDim.x + threadIdx.x; i < n8; i += stride) {
        const float4* p = (const float4*)x + (size_t)i * 2;
        float4 a = p[0], b = p[1];
        uint4 o;
        o.x = (uint32_t)f32_to_bf16_rne(a.x) | ((uint32_t)f32_to_bf16_rne(a.y) << 16);
        o.y = (uint32_t)f32_to_bf16_rne(a.z) | ((uint32_t)f32_to_bf16_rne(a.w) << 16);
        o.z = (uint32_t)f32_to_bf16_rne(b.x) | ((uint32_t)f32_to_bf16_rne(b.y) << 16);
        o.w = (uint32_t)f32_to_bf16_rne(b.z) | ((uint32_t)f32_to_bf16_rne(b.w) << 16);
        ((uint4*)xb)[i] = o;
    }
}

__global__ void convert_w_kernel(const float* __restrict__ w,
                                 unsigned short* __restrict__ wb, int n8) {
    int stride = gridDim.x * blockDim.x;
    for (int i = blockIdx.x * blockDim.x + threadIdx.x; i < n8; i += stride) {
        const float4* p = (const float4*)w + (size_t)i * 2;
        float4 a = p[0], b = p[1];
        uint4 o;
        o.x = (uint32_t)sign_to_bf16(a.x) | ((uint32_t)sign_to_bf16(a.y) << 16);
        o.y = (uint32_t)sign_to_bf16(a.z) | ((uint32_t)sign_to_bf16(a.w) << 16);
        o.z = (uint32_t)sign_to_bf16(b.x) | ((uint32_t)sign_to_bf16(b.y) << 16);
        o.w = (uint32_t)sign_to_bf16(b.z) | ((uint32_t)sign_to_bf16(b.w) << 16);
        ((uint4*)wb)[i] = o;
    }
}

// ---- Phase 2: 256x256-tile 8-phase GEMM, 32x32x16 MFMA, k-split phases ----
// C = Xb (M x K) * Wb^T (K x N) + bias; Xb row-major MxK, Wb row-major NxK.
// LDS: [2 buf][4 sect: A0,A1,B0,B1][128 rows x 64 cols bf16] = 128 KiB.
// XOR-swizzle T2: logical (row, colbyte) stored at colbyte ^ ((row&7)<<4).
// Per K-tile: 4 phases = ksteps 0..3; reads 8/8/4/4 b128; 8 MFMA 32x32x16 each.
// B-frags (all ksteps) front-loaded P1/P2 so P3/P4's B(t+2) stages are race-free.

#define BAR   __builtin_amdgcn_s_barrier()
#define SCB0  __builtin_amdgcn_sched_barrier(0)
#define LGKM0 asm volatile("s_waitcnt lgkmcnt(0)" ::: "memory")
#define VM4   asm volatile("s_waitcnt vmcnt(4)" ::: "memory")
#define VM0   asm volatile("s_waitcnt vmcnt(0)" ::: "memory")

#define RDA4(BUFV, KS) \
    _Pragma("unroll") for (int mm = 0; mm < 4; ++mm) \
        a[mm] = rdfrag((BUFV), wm, mm * 32, (KS));

#define RDB2(BUFV, KS) \
    _Pragma("unroll") for (int nn = 0; nn < 2; ++nn) \
        b[nn][(KS)] = rdfrag((BUFV), sectB, rB + nn * 32, (KS));

#define MM8(KS) \
    __builtin_amdgcn_s_setprio(1); \
    _Pragma("unroll") for (int mm = 0; mm < 4; ++mm) \
    _Pragma("unroll") for (int nn = 0; nn < 2; ++nn) \
        acc[mm][nn] = __builtin_amdgcn_mfma_f32_32x32x16_bf16( \
            a[mm], b[nn][(KS)], acc[mm][nn], 0, 0, 0); \
    __builtin_amdgcn_s_setprio(0);

// One K-tile t. P1/P2 stage A-halves of t+1 (other buffer);
// P3/P4 stage B-halves of t+2 (current buffer; all B reads of cur done at P2).
#define KT(T, SA, SB, VMW) do { \
    const int buf_ = (T) & 1; const int nbuf_ = buf_ ^ 1; \
    RDB2(buf_, 0) RDB2(buf_, 1) RDA4(buf_, 0) \
    if (SA) stage(nbuf_, 0, xb, brow, ((T) + 1) * 64); \
    BAR; LGKM0; SCB0; \
    MM8(0) \
    BAR; SCB0; \
    RDB2(buf_, 2) RDB2(buf_, 3) RDA4(buf_, 1) \
    if (SA) stage(nbuf_, 1, xb, brow + 128, ((T) + 1) * 64); \
    BAR; LGKM0; SCB0; \
    MM8(1) \
    BAR; SCB0; \
    RDA4(buf_, 2) \
    if (SB) stage(buf_, 2, wb, bcol, ((T) + 2) * 64); \
    BAR; LGKM0; SCB0; \
    MM8(2) \
    BAR; SCB0; \
    RDA4(buf_, 3) \
    if (SB) stage(buf_, 3, wb, bcol + 128, ((T) + 2) * 64); \
    BAR; LGKM0; SCB0; \
    MM8(3) \
    VMW; \
    BAR; SCB0; \
} while (0)

__global__ __launch_bounds__(512, 2)
void gemm_bin_kernel(const unsigned short* __restrict__ xb,
                     const unsigned short* __restrict__ wb,
                     const float* __restrict__ bias,
                     float* __restrict__ out) {
    __shared__ __align__(16) unsigned short lds[2][4][8192];

    const int tid  = threadIdx.x;
    const int wid  = tid >> 6;
    const int lane = tid & 63;

    // XCD-aware swizzle: 512 blocks, 8 XCDs, 64 contiguous tiles per XCD
    const int bid  = blockIdx.x;
    const int swzb = (bid & 7) * 64 + (bid >> 3);
    const int brow = (swzb >> 4) * 256;      // 32 M-tiles
    const int bcol = (swzb & 15) * 256;      // 16 N-tiles

    const int wm = wid >> 2;                 // 0..1: A half (row block of 128)
    const int wn = wid & 3;                  // 0..3: 64-col block
    const int l31 = lane & 31;
    const int hi16 = (lane >> 5) << 4;       // k-group byte offset (32x32 frag)
    const int sw  = (lane & 7) << 4;         // T2 swizzle XOR == (row&7)<<4
    const int sectB = 2 + (wn >> 1);
    const int rB    = (wn & 1) * 64;

    f32x16 acc[4][2] = {};                   // 4 m-blocks x 2 n-blocks of 32x32
    bf16x8 a[4], b[2][4];

    // staging: half-tile 128x64 bf16, 16 chunks of 1KB; wave w -> chunks 2w,2w+1.
    // linear LDS dest; global source pre-swizzled: colE = ((lane&7)^(lane>>3))*8
    const int ssub  = lane >> 3;
    const int scolE = ((lane & 7) ^ ssub) * 8;
    auto stage = [&](int bufv, int sect, const unsigned short* g, int row0, int k0) {
        unsigned short* lb = &lds[bufv][sect][0];
        #pragma unroll
        for (int j = 0; j < 2; ++j) {
            const int c = wid * 2 + j;
            const int r = c * 8 + ssub;
            async16(g + (size_t)(row0 + r) * K_DIM + (k0 + scolE),
                    lb + c * 512 + lane * 8);
        }
    };

    // 32x32x16 frag read: row = rbase + (lane&31), kbyte = ks*32 + (lane>>5)*16
    auto rdfrag = [&](int bufv, int sect, int rbase, int ks) -> bf16x8 {
        const char* base = (const char*)&lds[bufv][sect][0];
        const int off = (rbase + l31) * 128 + ((ks * 32 + hi16) ^ sw);
        return *(const bf16x8*)(base + off);
    };

    // prologue: K-tile 0 (A0,A1,B0,B1 -> buf0) + B-halves of K-tile 1 -> buf1
    stage(0, 0, xb, brow,        0);
    stage(0, 1, xb, brow + 128,  0);
    stage(0, 2, wb, bcol,        0);
    stage(0, 3, wb, bcol + 128,  0);
    stage(1, 2, wb, bcol,       64);
    stage(1, 3, wb, bcol + 128, 64);
    VM4;                 // K-tile 0 fully landed; B(1) halves may be in flight
    BAR; SCB0;

    #pragma unroll 2
    for (int t = 0; t < NT - 2; ++t) KT(t, 1, 1, VM4);
    KT(NT - 2, 1, 0, VM0);           // stage A(63) only; drain before last tile
    KT(NT - 1, 0, 0, (void)0);       // pure compute

    // epilogue: 32x32 C/D layout: col = lane&31, row = (reg&3)+8*(reg>>2)+4*(lane>>5)
    const int wrow = wm * 128, wcol = wn * 64;
    const int h4 = (lane >> 5) * 4;
    float bv[2];
    #pragma unroll
    for (int nb = 0; nb < 2; ++nb) bv[nb] = bias[bcol + wcol + nb * 32 + l31];
    #pragma unroll
    for (int mb = 0; mb < 4; ++mb) {
        #pragma unroll
        for (int rg = 0; rg < 4; ++rg) {
            #pragma unroll
            for (int rr = 0; rr < 4; ++rr) {
                const int row = brow + wrow + mb * 32 + rg * 8 + h4 + rr;
                float* orow = out + (size_t)row * N_DIM + bcol + wcol;
                #pragma unroll
                for (int nb = 0; nb < 2; ++nb)
                    orow[nb * 32 + l31] = acc[mb][nb][rg * 4 + rr] + bv[nb];
            }
        }
    }
}

// ---- Fallback if ws too small: naive fp32 (correct, slow; safety net) ----

__global__ void naive_kernel(const float* __restrict__ x,
                             const float* __restrict__ w,
                             const float* __restrict__ bias,
                             float* __restrict__ out) {
    const size_t total = (size_t)M_DIM * N_DIM;
    for (size_t idx = (size_t)blockIdx.x * blockDim.x + threadIdx.x; idx < total;
         idx += (size_t)gridDim.x * blockDim.x) {
        const size_t row = idx >> 12;
        const size_t col = idx & 4095;
        const float4* xr  = (const float4*)(x + row * K_DIM);
        const float4* wrp = (const float4*)(w + col * K_DIM);
        float s = 0.f;
        for (int k = 0; k < K_DIM / 4; ++k) {
            float4 a = xr[k], bq = wrp[k];
            s += a.x * (bq.x > 0.f ? 1.f : (bq.x < 0.f ? -1.f : 0.f));
            s += a.y * (bq.y > 0.f ? 1.f : (bq.y < 0.f ? -1.f : 0.f));
            s += a.z * (bq.z > 0.f ? 1.f : (bq.z < 0.f ? -1.f : 0.f));
            s += a.w * (bq.w > 0.f ? 1.f : (bq.w < 0.f ? -1.f : 0.f));
        }
        out[idx] = s + bias[col];
    }
}

extern "C" void kernel_launch(void* const* d_in, const int* in_sizes, int n_in,
                              void* d_out, int out_size, void* d_ws, size_t ws_size,
                              hipStream_t stream) {
    const float* x    = (const float*)d_in[0];
    const float* w    = (const float*)d_in[1];
    const float* bias = (const float*)d_in[2];
    float* out = (float*)d_out;

    const size_t xb_bytes = (size_t)M_DIM * K_DIM * 2;   // 64 MB
    const size_t wb_bytes = (size_t)N_DIM * K_DIM * 2;   // 32 MB

    if (ws_size >= xb_bytes + wb_bytes) {
        unsigned short* xb = (unsigned short*)d_ws;
        unsigned short* wb = (unsigned short*)((char*)d_ws + xb_bytes);
        convert_x_kernel<<<2048, 256, 0, stream>>>(x, xb, (int)((size_t)M_DIM * K_DIM / 8));
        convert_w_kernel<<<2048, 256, 0, stream>>>(w, wb, (int)((size_t)N_DIM * K_DIM / 8));
        gemm_bin_kernel<<<dim3((M_DIM / 256) * (N_DIM / 256)), dim3(512), 0, stream>>>(
            xb, wb, bias, out);
    } else {
        naive_kernel<<<4096, 256, 0, stream>>>(x, w, bias, out);
    }
}

// Round 4
// 267.053 us; speedup vs baseline: 1.0633x; 1.0633x over previous
//
#include <hip/hip_runtime.h>
#include <hip/hip_bf16.h>
#include <stdint.h>

#define M_DIM 8192
#define N_DIM 4096
#define K_DIM 4096

#define NT 64              // K-tiles of BK=64

using f32x4  = __attribute__((ext_vector_type(4))) float;
using bf16x8 = __attribute__((ext_vector_type(8))) __bf16;

typedef const __attribute__((address_space(1))) void glb_void_t;
typedef __attribute__((address_space(3))) void lds_void_t;

__device__ __forceinline__ void async16(const void* g, void* l) {
    // direct global->LDS, 16B per lane (dest = wave-uniform base + lane*16)
    __builtin_amdgcn_global_load_lds((glb_void_t*)(uintptr_t)g,
                                     (lds_void_t*)(uint32_t)(uintptr_t)l,
                                     16, 0, 0);
}

__device__ __forceinline__ unsigned short f32_to_bf16_rne(float f) {
    union { float f; uint32_t u; } v; v.f = f;
    uint32_t u = v.u;
    u += 0x7FFFu + ((u >> 16) & 1u);
    return (unsigned short)(u >> 16);
}

__device__ __forceinline__ unsigned short sign_to_bf16(float f) {
    union { float f; uint32_t u; } v; v.f = f;
    if ((v.u & 0x7FFFFFFFu) == 0u) return 0;                      // sign(0) = 0
    return (unsigned short)(0x3F80u | ((v.u >> 16) & 0x8000u));   // +-1.0 bf16
}

// ---- Phase 1: conversions (memory-bound, 16B loads / 16B stores) ----

__global__ void convert_x_kernel(const float* __restrict__ x,
                                 unsigned short* __restrict__ xb, int n8) {
    int stride = gridDim.x * blockDim.x;
    for (int i = blockIdx.x * blockDim.x + threadIdx.x; i < n8; i += stride) {
        const float4* p = (const float4*)x + (size_t)i * 2;
        float4 a = p[0], b = p[1];
        uint4 o;
        o.x = (uint32_t)f32_to_bf16_rne(a.x) | ((uint32_t)f32_to_bf16_rne(a.y) << 16);
        o.y = (uint32_t)f32_to_bf16_rne(a.z) | ((uint32_t)f32_to_bf16_rne(a.w) << 16);
        o.z = (uint32_t)f32_to_bf16_rne(b.x) | ((uint32_t)f32_to_bf16_rne(b.y) << 16);
        o.w = (uint32_t)f32_to_bf16_rne(b.z) | ((uint32_t)f32_to_bf16_rne(b.w) << 16);
        ((uint4*)xb)[i] = o;
    }
}

__global__ void convert_w_kernel(const float* __restrict__ w,
                                 unsigned short* __restrict__ wb, int n8) {
    int stride = gridDim.x * blockDim.x;
    for (int i = blockIdx.x * blockDim.x + threadIdx.x; i < n8; i += stride) {
        const float4* p = (const float4*)w + (size_t)i * 2;
        float4 a = p[0], b = p[1];
        uint4 o;
        o.x = (uint32_t)sign_to_bf16(a.x) | ((uint32_t)sign_to_bf16(a.y) << 16);
        o.y = (uint32_t)sign_to_bf16(a.z) | ((uint32_t)sign_to_bf16(a.w) << 16);
        o.z = (uint32_t)sign_to_bf16(b.x) | ((uint32_t)sign_to_bf16(b.y) << 16);
        o.w = (uint32_t)sign_to_bf16(b.z) | ((uint32_t)sign_to_bf16(b.w) << 16);
        ((uint4*)wb)[i] = o;
    }
}

// ---- Phase 2: 256x256-tile 8-phase GEMM, 16x16x32 MFMA, balanced phases ----
// C = Xb (M x K) * Wb^T (K x N) + bias; Xb row-major MxK, Wb row-major NxK.
// LDS: [2 buf][4 sect: A0,A1,B0,B1][128 rows x 64 cols bf16] = 128 KiB.
// XOR-swizzle T2 (16x16-read conflict-free, round-2-proven):
//   logical (row, colbyte) stored at colbyte ^ ((row&7)<<4).
// Per K-tile: 4 phases, reads 8/8/4/4 b128, 16 MFMA each:
//   P1 rows0-3 k0 (a0-3k0 + all b k0), P2 rows0-3 k1 (a0-3k1 + all b k1),
//   P3 rows4-7 k0 (a4-7k0),            P4 rows4-7 k1 (a4-7k1).
// All B reads done by P2 end -> P3/P4 stage B(t+2) into live buffer race-free.

#define BAR   __builtin_amdgcn_s_barrier()
#define SCB0  __builtin_amdgcn_sched_barrier(0)
#define LGKM0 asm volatile("s_waitcnt lgkmcnt(0)" ::: "memory")
#define VM4   asm volatile("s_waitcnt vmcnt(4)" ::: "memory")
#define VM0   asm volatile("s_waitcnt vmcnt(0)" ::: "memory")

#define RDA(BUFV, MLO, KK) \
    _Pragma("unroll") for (int mm = 0; mm < 4; ++mm) \
        a[mm] = rdfrag((BUFV), wm, ((MLO) + mm) * 16, (KK));

#define RDB(BUFV, KK) \
    _Pragma("unroll") for (int nn = 0; nn < 4; ++nn) \
        b[nn][(KK)] = rdfrag((BUFV), sectB, rB + nn * 16, (KK));

#define MM16R(MB, KK) \
    __builtin_amdgcn_s_setprio(1); \
    _Pragma("unroll") for (int mm = 0; mm < 4; ++mm) \
    _Pragma("unroll") for (int nn = 0; nn < 4; ++nn) \
        acc[(MB) + mm][nn] = __builtin_amdgcn_mfma_f32_16x16x32_bf16( \
            a[mm], b[nn][(KK)], acc[(MB) + mm][nn], 0, 0, 0); \
    __builtin_amdgcn_s_setprio(0);

// One K-tile t. P1/P2 stage A-halves of t+1 (other buffer);
// P3/P4 stage B-halves of t+2 (current buffer; all B reads of cur done at P2).
#define KT(T, SA, SB, VMW) do { \
    const int buf_ = (T) & 1; const int nbuf_ = buf_ ^ 1; \
    RDA(buf_, 0, 0) RDB(buf_, 0) \
    if (SA) stage(nbuf_, 0, xb, brow, ((T) + 1) * 64); \
    BAR; LGKM0; SCB0; \
    MM16R(0, 0) \
    BAR; SCB0; \
    RDA(buf_, 0, 1) RDB(buf_, 1) \
    if (SA) stage(nbuf_, 1, xb, brow + 128, ((T) + 1) * 64); \
    BAR; LGKM0; SCB0; \
    MM16R(0, 1) \
    BAR; SCB0; \
    RDA(buf_, 4, 0) \
    if (SB) stage(buf_, 2, wb, bcol, ((T) + 2) * 64); \
    BAR; LGKM0; SCB0; \
    MM16R(4, 0) \
    BAR; SCB0; \
    RDA(buf_, 4, 1) \
    if (SB) stage(buf_, 3, wb, bcol + 128, ((T) + 2) * 64); \
    BAR; LGKM0; SCB0; \
    MM16R(4, 1) \
    VMW; \
    BAR; SCB0; \
} while (0)

__global__ __launch_bounds__(512, 2)
void gemm_bin_kernel(const unsigned short* __restrict__ xb,
                     const unsigned short* __restrict__ wb,
                     const float* __restrict__ bias,
                     float* __restrict__ out) {
    __shared__ __align__(16) unsigned short lds[2][4][8192];

    const int tid  = threadIdx.x;
    const int wid  = tid >> 6;
    const int lane = tid & 63;

    // XCD-aware swizzle: 512 blocks, 8 XCDs, 64 contiguous tiles per XCD
    const int bid  = blockIdx.x;
    const int swzb = (bid & 7) * 64 + (bid >> 3);
    const int brow = (swzb >> 4) * 256;      // 32 M-tiles
    const int bcol = (swzb & 15) * 256;      // 16 N-tiles

    const int wm = wid >> 2;                 // 0..1: A half (row block of 128)
    const int wn = wid & 3;                  // 0..3: 64-col block
    const int fr  = lane & 15;
    const int g16 = (lane >> 4) << 4;        // k-group byte offset (16x16 frag)
    const int sw  = (lane & 7) << 4;         // T2 swizzle XOR == (row&7)<<4
    const int sectB = 2 + (wn >> 1);
    const int rB    = (wn & 1) * 64;

    f32x4  acc[8][4] = {};
    bf16x8 a[4], b[4][2];

    // staging: half-tile 128x64 bf16, 16 chunks of 1KB; wave w -> chunks 2w,2w+1.
    // linear LDS dest; global source pre-swizzled: colE = ((lane&7)^(lane>>3))*8
    const int ssub  = lane >> 3;
    const int scolE = ((lane & 7) ^ ssub) * 8;
    auto stage = [&](int bufv, int sect, const unsigned short* g, int row0, int k0) {
        unsigned short* lb = &lds[bufv][sect][0];
        #pragma unroll
        for (int j = 0; j < 2; ++j) {
            const int c = wid * 2 + j;
            const int r = c * 8 + ssub;
            async16(g + (size_t)(row0 + r) * K_DIM + (k0 + scolE),
                    lb + c * 512 + lane * 8);
        }
    };

    // 16x16 frag read: row = rbase + (lane&15), kbyte = kk*64 + (lane>>4)*16
    auto rdfrag = [&](int bufv, int sect, int rbase, int kk) -> bf16x8 {
        const char* base = (const char*)&lds[bufv][sect][0];
        const int off = (rbase + fr) * 128 + (((kk * 64) + g16) ^ sw);
        return *(const bf16x8*)(base + off);
    };

    // prologue: K-tile 0 (A0,A1,B0,B1 -> buf0) + B-halves of K-tile 1 -> buf1
    stage(0, 0, xb, brow,        0);
    stage(0, 1, xb, brow + 128,  0);
    stage(0, 2, wb, bcol,        0);
    stage(0, 3, wb, bcol + 128,  0);
    stage(1, 2, wb, bcol,       64);
    stage(1, 3, wb, bcol + 128, 64);
    VM4;                 // K-tile 0 fully landed; B(1) halves may be in flight
    BAR; SCB0;

    #pragma unroll 2
    for (int t = 0; t < NT - 2; ++t) KT(t, 1, 1, VM4);
    KT(NT - 2, 1, 0, VM0);           // stage A(63) only; drain before last tile
    KT(NT - 1, 0, 0, (void)0);       // pure compute

    // epilogue: C/D layout col = lane&15, row = (lane>>4)*4 + reg
    const int wrow = wm * 128, wcol = wn * 64;
    float bv[4];
    #pragma unroll
    for (int n = 0; n < 4; ++n) bv[n] = bias[bcol + wcol + n * 16 + fr];
    const int r4 = (lane >> 4) * 4;
    #pragma unroll
    for (int m = 0; m < 8; ++m) {
        #pragma unroll
        for (int rr = 0; rr < 4; ++rr) {
            const int row = brow + wrow + m * 16 + r4 + rr;
            float* orow = out + (size_t)row * N_DIM + bcol + wcol;
            #pragma unroll
            for (int n = 0; n < 4; ++n)
                orow[n * 16 + fr] = acc[m][n][rr] + bv[n];
        }
    }
}

// ---- Fallback if ws too small: naive fp32 (correct, slow; safety net) ----

__global__ void naive_kernel(const float* __restrict__ x,
                             const float* __restrict__ w,
                             const float* __restrict__ bias,
                             float* __restrict__ out) {
    const size_t total = (size_t)M_DIM * N_DIM;
    for (size_t idx = (size_t)blockIdx.x * blockDim.x + threadIdx.x; idx < total;
         idx += (size_t)gridDim.x * blockDim.x) {
        const size_t row = idx >> 12;
        const size_t col = idx & 4095;
        const float4* xr  = (const float4*)(x + row * K_DIM);
        const float4* wrp = (const float4*)(w + col * K_DIM);
        float s = 0.f;
        for (int k = 0; k < K_DIM / 4; ++k) {
            float4 a = xr[k], bq = wrp[k];
            s += a.x * (bq.x > 0.f ? 1.f : (bq.x < 0.f ? -1.f : 0.f));
            s += a.y * (bq.y > 0.f ? 1.f : (bq.y < 0.f ? -1.f : 0.f));
            s += a.z * (bq.z > 0.f ? 1.f : (bq.z < 0.f ? -1.f : 0.f));
            s += a.w * (bq.w > 0.f ? 1.f : (bq.w < 0.f ? -1.f : 0.f));
        }
        out[idx] = s + bias[col];
    }
}

extern "C" void kernel_launch(void* const* d_in, const int* in_sizes, int n_in,
                              void* d_out, int out_size, void* d_ws, size_t ws_size,
                              hipStream_t stream) {
    const float* x    = (const float*)d_in[0];
    const float* w    = (const float*)d_in[1];
    const float* bias = (const float*)d_in[2];
    float* out = (float*)d_out;

    const size_t xb_bytes = (size_t)M_DIM * K_DIM * 2;   // 64 MB
    const size_t wb_bytes = (size_t)N_DIM * K_DIM * 2;   // 32 MB

    if (ws_size >= xb_bytes + wb_bytes) {
        unsigned short* xb = (unsigned short*)d_ws;
        unsigned short* wb = (unsigned short*)((char*)d_ws + xb_bytes);
        convert_x_kernel<<<2048, 256, 0, stream>>>(x, xb, (int)((size_t)M_DIM * K_DIM / 8));
        convert_w_kernel<<<2048, 256, 0, stream>>>(w, wb, (int)((size_t)N_DIM * K_DIM / 8));
        gemm_bin_kernel<<<dim3((M_DIM / 256) * (N_DIM / 256)), dim3(512), 0, stream>>>(
            xb, wb, bias, out);
    } else {
        naive_kernel<<<4096, 256, 0, stream>>>(x, w, bias, out);
    }
}